// Round 1
// 1664.314 us; speedup vs baseline: 1.0279x; 1.0279x over previous
//
#include <hip/hip_runtime.h>
#include <cmath>

#define MSG 128
#define TILE_M 128

typedef __attribute__((ext_vector_type(8))) __bf16 bf16x8;
typedef __attribute__((ext_vector_type(4))) float f32x4;

__device__ __forceinline__ unsigned short f2bf(float f) {
  union { float f; unsigned u; } v; v.f = f;
  unsigned r = v.u + 0x7FFFu + ((v.u >> 16) & 1u);  // round-to-nearest-even
  return (unsigned short)(r >> 16);
}

// ---- Kernel 1: convert + transpose both hidden-layer weight matrices to bf16.
// Wt[n][k] = W1[k][n] so MFMA fragments (contiguous in k) are vector loads.
__global__ void prep_weights_kernel(const float* __restrict__ Ww1,
                                    const float* __restrict__ Wa1,
                                    unsigned short* __restrict__ WtW,
                                    unsigned short* __restrict__ WtA) {
  int idx = blockIdx.x * blockDim.x + threadIdx.x;
  if (idx < MSG * MSG) {
    int k = idx >> 7;
    int n = idx & 127;
    WtW[n * MSG + k] = f2bf(Ww1[idx]);
    WtA[n * MSG + k] = f2bf(Wa1[idx]);
  }
}

// ---- Kernel 2: fused edge MLPs (weights + attention) via bf16 MFMA.
// LDS-free, operand-swapped layout:
//   A = Wt (weights, transposed)  ->  A[m = hidden unit][k]
//   B = m_ij (per-edge features)  ->  B[k][n = edge]
//   D[m = hidden unit][n = edge]  ->  C cols are edges => epilogue reduction is
//   2 shuffles (across quads) and the writeback is 32 contiguous lanes.
// Each wave owns 32 edges (two 16-edge column tiles). m-fragments are loaded
// from global straight into registers (f32 -> bf16 via cvt_pk) and reused by
// both MLPs. No LDS, no __syncthreads, no bank conflicts.
__global__ __launch_bounds__(256, 3)
void edge_mlp_kernel(const float* __restrict__ m_ij,
                     const unsigned short* __restrict__ WtW,
                     const unsigned short* __restrict__ WtA,
                     const float* __restrict__ bw1, const float* __restrict__ Ww2,
                     const float* __restrict__ bw2,
                     const float* __restrict__ ba1, const float* __restrict__ Wa2,
                     const float* __restrict__ ba2,
                     const int* __restrict__ src,
                     float* __restrict__ w_raw, float* __restrict__ a_ij,
                     float* __restrict__ a_i, int E) {
  const int tid = threadIdx.x;
  const int wv = tid >> 6;
  const int lane = tid & 63;
  const int quad = lane >> 4;
  const int l16 = lane & 15;
  const int ebase = blockIdx.x * TILE_M + wv * 32;

  // Load this wave's 32 edges of m_ij directly into MFMA B-fragments.
  // Lane holds B[k = quad*8 + kt*32 + j][n = l16], edge = ebase + et*16 + l16.
  bf16x8 mfrag[2][4];
  #pragma unroll
  for (int et = 0; et < 2; ++et) {
    int e = ebase + et * 16 + l16;
    if (e >= E) e = E - 1;  // clamp (stores are guarded)
    const float* row = m_ij + (size_t)e * MSG + quad * 8;
    #pragma unroll
    for (int kt = 0; kt < 4; ++kt) {
      const float4 v0 = *(const float4*)(row + kt * 32);
      const float4 v1 = *(const float4*)(row + kt * 32 + 4);
      bf16x8 f;
      f[0] = (__bf16)v0.x; f[1] = (__bf16)v0.y;
      f[2] = (__bf16)v0.z; f[3] = (__bf16)v0.w;
      f[4] = (__bf16)v1.x; f[5] = (__bf16)v1.y;
      f[6] = (__bf16)v1.z; f[7] = (__bf16)v1.w;
      mfrag[et][kt] = f;
    }
  }

  auto run_mlp = [&](const unsigned short* __restrict__ Wt,
                     const float* __restrict__ b1, const float* __restrict__ W2,
                     float b2, bool isAtt) {
    f32x4 acc[2][8];
    #pragma unroll
    for (int et = 0; et < 2; ++et)
      #pragma unroll
      for (int nt = 0; nt < 8; ++nt)
        acc[et][nt] = {0.f, 0.f, 0.f, 0.f};

    // A-fragment: A[m = l16 (+nt*16)][k = quad*8 + kt*32 + j] = Wt[m][k].
    #pragma unroll
    for (int nt = 0; nt < 8; ++nt) {
      const unsigned short* arow = Wt + (size_t)(nt * 16 + l16) * MSG + quad * 8;
      #pragma unroll
      for (int kt = 0; kt < 4; ++kt) {
        const bf16x8 A = *(const bf16x8*)(arow + kt * 32);
        acc[0][nt] = __builtin_amdgcn_mfma_f32_16x16x32_bf16(A, mfrag[0][kt], acc[0][nt], 0, 0, 0);
        acc[1][nt] = __builtin_amdgcn_mfma_f32_16x16x32_bf16(A, mfrag[1][kt], acc[1][nt], 0, 0, 0);
      }
    }

    // Epilogue: lane holds hidden units (nt*16 + quad*4 + r) of edge
    // (ebase + et*16 + l16). Fuse SiLU + dot with W2 per-lane, then sum the
    // 4 quads (disjoint hidden units, same edge) with 2 shuffles.
    float part0 = 0.f, part1 = 0.f;
    #pragma unroll
    for (int nt = 0; nt < 8; ++nt) {
      const float4 b1q = *(const float4*)(b1 + nt * 16 + quad * 4);
      const float4 w2q = *(const float4*)(W2 + nt * 16 + quad * 4);
      const float b1a[4] = {b1q.x, b1q.y, b1q.z, b1q.w};
      const float w2a[4] = {w2q.x, w2q.y, w2q.z, w2q.w};
      #pragma unroll
      for (int r = 0; r < 4; ++r) {
        float h0 = acc[0][nt][r] + b1a[r];
        float h1 = acc[1][nt][r] + b1a[r];
        part0 += (h0 / (1.f + __expf(-h0))) * w2a[r];  // silu(h)*W2
        part1 += (h1 / (1.f + __expf(-h1))) * w2a[r];
      }
    }
    part0 += __shfl_xor(part0, 16, 64);
    part0 += __shfl_xor(part0, 32, 64);
    part1 += __shfl_xor(part1, 16, 64);
    part1 += __shfl_xor(part1, 32, 64);

    // Lanes 0..31 write 32 consecutive edges (coalesced).
    if (lane < 32) {
      float val = (lane < 16 ? part0 : part1) + b2;
      int e = ebase + lane;
      if (e < E) {
        if (isAtt) {
          float a = __expf(val);
          a_ij[e] = a;
          atomicAdd(&a_i[src[e]], a);
        } else {
          w_raw[e] = val;
        }
      }
    }
  };

  run_mlp(WtW, bw1, Ww2, bw2[0], false);
  run_mlp(WtA, ba1, Wa2, ba2[0], true);
}

// ---- Kernel 3: per-edge scatter of weighted unit position differences.
__global__ void scatter_kernel(const float* __restrict__ x,
                               const int* __restrict__ src,
                               const int* __restrict__ dst,
                               const float* __restrict__ w_raw,
                               const float* __restrict__ a_ij,
                               const float* __restrict__ a_i,
                               float* __restrict__ out, int E) {
  int e = blockIdx.x * blockDim.x + threadIdx.x;
  if (e >= E) return;
  int s = src[e];
  int d = dst[e];
  float w = w_raw[e] * (a_ij[e] / a_i[s]);
  float sx = x[3 * s], sy = x[3 * s + 1], sz = x[3 * s + 2];
  float dx = x[3 * d] - sx;
  float dy = x[3 * d + 1] - sy;
  float dz = x[3 * d + 2] - sz;
  float nrm = sqrtf(dx * dx + dy * dy + dz * dz);
  nrm = fmaxf(nrm, 1e-12f);
  float inv = w / nrm;
  atomicAdd(&out[3 * s + 0], dx * inv);
  atomicAdd(&out[3 * s + 1], dy * inv);
  atomicAdd(&out[3 * s + 2], dz * inv);
}

extern "C" void kernel_launch(void* const* d_in, const int* in_sizes, int n_in,
                              void* d_out, int out_size, void* d_ws, size_t ws_size,
                              hipStream_t stream) {
  const float* x    = (const float*)d_in[0];
  const float* m_ij = (const float*)d_in[1];
  const int*   edges = (const int*)d_in[2];
  const float* Ww1 = (const float*)d_in[3];
  const float* bw1 = (const float*)d_in[4];
  const float* Ww2 = (const float*)d_in[5];
  const float* bw2 = (const float*)d_in[6];
  const float* Wa1 = (const float*)d_in[7];
  const float* ba1 = (const float*)d_in[8];
  const float* Wa2 = (const float*)d_in[9];
  const float* ba2 = (const float*)d_in[10];

  const int N = in_sizes[0] / 3;
  const int E = in_sizes[1] / MSG;
  const int* src = edges;        // edges[0] = receiver
  const int* dst = edges + E;    // edges[1] = neighbor

  // Workspace layout (~13.3 MB)
  char* p = (char*)d_ws;
  unsigned short* WtW = (unsigned short*)p; p += (size_t)MSG * MSG * 2;
  unsigned short* WtA = (unsigned short*)p; p += (size_t)MSG * MSG * 2;
  float* w_raw = (float*)p; p += (size_t)E * 4;
  float* aij   = (float*)p; p += (size_t)E * 4;
  float* ai    = (float*)p; p += (size_t)N * 4;

  float* out = (float*)d_out;

  hipMemsetAsync(ai, 0, (size_t)N * 4, stream);
  prep_weights_kernel<<<(MSG * MSG + 255) / 256, 256, 0, stream>>>(Ww1, Wa1, WtW, WtA);
  edge_mlp_kernel<<<(E + TILE_M - 1) / TILE_M, 256, 0, stream>>>(
      m_ij, WtW, WtA, bw1, Ww2, bw2, ba1, Wa2, ba2, src, w_raw, aij, ai, E);
  hipMemcpyAsync(out, x, (size_t)N * 3 * sizeof(float), hipMemcpyDeviceToDevice, stream);
  scatter_kernel<<<(E + 255) / 256, 256, 0, stream>>>(x, src, dst, w_raw, aij, ai, out, E);
}

// Round 2
// 1526.636 us; speedup vs baseline: 1.1206x; 1.0902x over previous
//
#include <hip/hip_runtime.h>
#include <cmath>

#define MSG 128
#define TILE_M 128

typedef __attribute__((ext_vector_type(8))) __bf16 bf16x8;
typedef __attribute__((ext_vector_type(4))) float f32x4;

__device__ __forceinline__ unsigned short f2bf(float f) {
  union { float f; unsigned u; } v; v.f = f;
  unsigned r = v.u + 0x7FFFu + ((v.u >> 16) & 1u);  // round-to-nearest-even
  return (unsigned short)(r >> 16);
}

// ---- Kernel 1: convert + transpose both hidden-layer weight matrices to bf16.
// Wt[n][k] = W1[k][n] so MFMA fragments (contiguous in k) are vector loads.
__global__ void prep_weights_kernel(const float* __restrict__ Ww1,
                                    const float* __restrict__ Wa1,
                                    unsigned short* __restrict__ WtW,
                                    unsigned short* __restrict__ WtA) {
  int idx = blockIdx.x * blockDim.x + threadIdx.x;
  if (idx < MSG * MSG) {
    int k = idx >> 7;
    int n = idx & 127;
    WtW[n * MSG + k] = f2bf(Ww1[idx]);
    WtA[n * MSG + k] = f2bf(Wa1[idx]);
  }
}

// ---- Kernel 2: fully fused edge pass.
// Both MLPs via bf16 MFMA (operand-swapped: A=weights, B=edges, D cols=edges),
// then the scatter is fused into the epilogue using the algebraic identity
//   sum_e (w_e * a_e / a_i[s]) * dir_e = (1/a_i[s]) * sum_e (w_e * a_e * dir_e)
// (a_i[s] is constant within a segment), so no grid-wide dependency on a_i.
// Random gathers + atomics hide under the MFMA/VALU work of neighboring waves.
__global__ __launch_bounds__(256, 3)
void edge_mlp_fused_kernel(const float* __restrict__ m_ij,
                           const unsigned short* __restrict__ WtW,
                           const unsigned short* __restrict__ WtA,
                           const float* __restrict__ bw1, const float* __restrict__ Ww2,
                           const float* __restrict__ bw2,
                           const float* __restrict__ ba1, const float* __restrict__ Wa2,
                           const float* __restrict__ ba2,
                           const int* __restrict__ src,
                           const int* __restrict__ dst,
                           const float* __restrict__ x,
                           float* __restrict__ a_i,
                           float* __restrict__ num, int E) {
  const int tid = threadIdx.x;
  const int wv = tid >> 6;
  const int lane = tid & 63;
  const int quad = lane >> 4;
  const int l16 = lane & 15;
  const int ebase = blockIdx.x * TILE_M + wv * 32;

  // Load this wave's 32 edges of m_ij directly into MFMA B-fragments.
  // Lane holds B[k = quad*8 + kt*32 + j][n = l16], edge = ebase + et*16 + l16.
  bf16x8 mfrag[2][4];
  #pragma unroll
  for (int et = 0; et < 2; ++et) {
    int e = ebase + et * 16 + l16;
    if (e >= E) e = E - 1;  // clamp (stores are guarded)
    const float* row = m_ij + (size_t)e * MSG + quad * 8;
    #pragma unroll
    for (int kt = 0; kt < 4; ++kt) {
      const float4 v0 = *(const float4*)(row + kt * 32);
      const float4 v1 = *(const float4*)(row + kt * 32 + 4);
      bf16x8 f;
      f[0] = (__bf16)v0.x; f[1] = (__bf16)v0.y;
      f[2] = (__bf16)v0.z; f[3] = (__bf16)v0.w;
      f[4] = (__bf16)v1.x; f[5] = (__bf16)v1.y;
      f[6] = (__bf16)v1.z; f[7] = (__bf16)v1.w;
      mfrag[et][kt] = f;
    }
  }

  // Returns the fused-MLP output for edge (ebase + lane) on lanes 0..31
  // (undefined on lanes 32..63). No fdiv: silu via v_rcp_f32.
  auto run_mlp = [&](const unsigned short* __restrict__ Wt,
                     const float* __restrict__ b1,
                     const float* __restrict__ W2) -> float {
    f32x4 acc[2][8];
    #pragma unroll
    for (int et = 0; et < 2; ++et)
      #pragma unroll
      for (int nt = 0; nt < 8; ++nt)
        acc[et][nt] = {0.f, 0.f, 0.f, 0.f};

    // A-fragment: A[m = l16 (+nt*16)][k = quad*8 + kt*32 + j] = Wt[m][k].
    #pragma unroll
    for (int nt = 0; nt < 8; ++nt) {
      const unsigned short* arow = Wt + (size_t)(nt * 16 + l16) * MSG + quad * 8;
      #pragma unroll
      for (int kt = 0; kt < 4; ++kt) {
        const bf16x8 A = *(const bf16x8*)(arow + kt * 32);
        acc[0][nt] = __builtin_amdgcn_mfma_f32_16x16x32_bf16(A, mfrag[0][kt], acc[0][nt], 0, 0, 0);
        acc[1][nt] = __builtin_amdgcn_mfma_f32_16x16x32_bf16(A, mfrag[1][kt], acc[1][nt], 0, 0, 0);
      }
    }

    // Epilogue: lane holds hidden units (nt*16 + quad*4 + r) of edge
    // (ebase + et*16 + l16). silu(h)*W2 per-lane, then sum the 4 quads
    // (disjoint hidden units, same edge) with 2 shuffles.
    float part0 = 0.f, part1 = 0.f;
    #pragma unroll
    for (int nt = 0; nt < 8; ++nt) {
      const float4 b1q = *(const float4*)(b1 + nt * 16 + quad * 4);
      const float4 w2q = *(const float4*)(W2 + nt * 16 + quad * 4);
      const float b1a[4] = {b1q.x, b1q.y, b1q.z, b1q.w};
      const float w2a[4] = {w2q.x, w2q.y, w2q.z, w2q.w};
      #pragma unroll
      for (int r = 0; r < 4; ++r) {
        float h0 = acc[0][nt][r] + b1a[r];
        float h1 = acc[1][nt][r] + b1a[r];
        // silu(h) = h * sigmoid(h); rcp is exact enough (≈1e-7 rel) and
        // saturation-safe: exp(-h)->inf => rcp->0 => silu->0.
        part0 += (h0 * w2a[r]) * __builtin_amdgcn_rcpf(1.f + __expf(-h0));
        part1 += (h1 * w2a[r]) * __builtin_amdgcn_rcpf(1.f + __expf(-h1));
      }
    }
    part0 += __shfl_xor(part0, 16, 64);
    part0 += __shfl_xor(part0, 32, 64);
    part1 += __shfl_xor(part1, 16, 64);
    part1 += __shfl_xor(part1, 32, 64);
    return (lane < 16) ? part0 : part1;
  };

  const float vW = run_mlp(WtW, bw1, Ww2) + bw2[0];
  const float vA = run_mlp(WtA, ba1, Wa2) + ba2[0];

  // Fused scatter: lanes 0..31 own 32 consecutive edges (coalesced src/dst).
  if (lane < 32) {
    const int e = ebase + lane;
    if (e < E) {
      const float a = __expf(vA);
      const int s = src[e];
      const int d = dst[e];
      atomicAdd(&a_i[s], a);
      const float t = vW * a;  // w_raw * a_ij  (division by a_i deferred)
      const float sx = x[3 * s], sy = x[3 * s + 1], sz = x[3 * s + 2];
      const float dx = x[3 * d] - sx;
      const float dy = x[3 * d + 1] - sy;
      const float dz = x[3 * d + 2] - sz;
      const float nrm = sqrtf(dx * dx + dy * dy + dz * dz);
      const float inv = t * __builtin_amdgcn_rcpf(fmaxf(nrm, 1e-12f));
      atomicAdd(&num[3 * s + 0], dx * inv);
      atomicAdd(&num[3 * s + 1], dy * inv);
      atomicAdd(&num[3 * s + 2], dz * inv);
    }
  }
}

// ---- Kernel 3: per-node finalize. out = x + num / a_i (0 if no edges).
__global__ void finalize_kernel(const float* __restrict__ x,
                                const float* __restrict__ num,
                                const float* __restrict__ a_i,
                                float* __restrict__ out, int N3) {
  int i = blockIdx.x * blockDim.x + threadIdx.x;
  if (i >= N3) return;
  const unsigned node = (unsigned)i / 3u;  // magic-mul, cheap
  const float ai = a_i[node];
  const float add = (ai != 0.f) ? num[i] * __builtin_amdgcn_rcpf(ai) : 0.f;
  out[i] = x[i] + add;
}

extern "C" void kernel_launch(void* const* d_in, const int* in_sizes, int n_in,
                              void* d_out, int out_size, void* d_ws, size_t ws_size,
                              hipStream_t stream) {
  const float* x    = (const float*)d_in[0];
  const float* m_ij = (const float*)d_in[1];
  const int*   edges = (const int*)d_in[2];
  const float* Ww1 = (const float*)d_in[3];
  const float* bw1 = (const float*)d_in[4];
  const float* Ww2 = (const float*)d_in[5];
  const float* bw2 = (const float*)d_in[6];
  const float* Wa1 = (const float*)d_in[7];
  const float* ba1 = (const float*)d_in[8];
  const float* Wa2 = (const float*)d_in[9];
  const float* ba2 = (const float*)d_in[10];

  const int N = in_sizes[0] / 3;
  const int E = in_sizes[1] / MSG;
  const int* src = edges;        // edges[0] = receiver
  const int* dst = edges + E;    // edges[1] = neighbor

  // Workspace layout (~1.7 MB)
  char* p = (char*)d_ws;
  unsigned short* WtW = (unsigned short*)p; p += (size_t)MSG * MSG * 2;
  unsigned short* WtA = (unsigned short*)p; p += (size_t)MSG * MSG * 2;
  float* ai  = (float*)p; p += (size_t)N * 4;
  float* num = (float*)p; p += (size_t)N * 3 * 4;

  float* out = (float*)d_out;

  hipMemsetAsync(ai, 0, (size_t)N * 4, stream);
  hipMemsetAsync(num, 0, (size_t)N * 3 * 4, stream);
  prep_weights_kernel<<<(MSG * MSG + 255) / 256, 256, 0, stream>>>(Ww1, Wa1, WtW, WtA);
  edge_mlp_fused_kernel<<<(E + TILE_M - 1) / TILE_M, 256, 0, stream>>>(
      m_ij, WtW, WtA, bw1, Ww2, bw2, ba1, Wa2, ba2, src, dst, x, ai, num, E);
  finalize_kernel<<<(N * 3 + 255) / 256, 256, 0, stream>>>(x, num, ai, out, N * 3);
}

// Round 3
// 1427.683 us; speedup vs baseline: 1.1982x; 1.0693x over previous
//
#include <hip/hip_runtime.h>
#include <cmath>

#define MSG 128
#define TILE_M 128

typedef __attribute__((ext_vector_type(8))) __bf16 bf16x8;
typedef __attribute__((ext_vector_type(4))) float f32x4;

__device__ __forceinline__ unsigned short f2bf(float f) {
  union { float f; unsigned u; } v; v.f = f;
  unsigned r = v.u + 0x7FFFu + ((v.u >> 16) & 1u);  // round-to-nearest-even
  return (unsigned short)(r >> 16);
}

// ---- Kernel 1: convert + transpose both hidden-layer weight matrices to bf16.
// Wt[n][k] = W1[k][n] so MFMA fragments (contiguous in k) are vector loads.
__global__ void prep_weights_kernel(const float* __restrict__ Ww1,
                                    const float* __restrict__ Wa1,
                                    unsigned short* __restrict__ WtW,
                                    unsigned short* __restrict__ WtA) {
  int idx = blockIdx.x * blockDim.x + threadIdx.x;
  if (idx < MSG * MSG) {
    int k = idx >> 7;
    int n = idx & 127;
    WtW[n * MSG + k] = f2bf(Ww1[idx]);
    WtA[n * MSG + k] = f2bf(Wa1[idx]);
  }
}

// ---- Kernel 2: fully fused edge pass (dual MLP + scatter).
// Operand-swapped MFMA: A = weights (rows = hidden units), B = m_ij (cols =
// edges), so D cols are edges. Both MLPs run in ONE nt-loop sharing the
// m-fragments; each nt's accumulators are consumed immediately by a fused
// silu*W2 partial sum (16 regs of acc instead of 64 -> higher occupancy and
// room to keep all 16 staging loads in flight).
// Scatter identity: sum_e (w_e*a_e/a_i[s])*dir_e = (1/a_i[s]) * sum_e
// w_e*a_e*dir_e, so the a_i division is deferred to a per-node finalize and
// all 4 atomics (num.xyz + a_i) land in one 16B slot of num4[s].
__global__ __launch_bounds__(256, 5)
void edge_mlp_fused_kernel(const float* __restrict__ m_ij,
                           const unsigned short* __restrict__ WtW,
                           const unsigned short* __restrict__ WtA,
                           const float* __restrict__ bw1, const float* __restrict__ Ww2,
                           const float* __restrict__ bw2,
                           const float* __restrict__ ba1, const float* __restrict__ Wa2,
                           const float* __restrict__ ba2,
                           const int* __restrict__ src,
                           const int* __restrict__ dst,
                           const float* __restrict__ x,
                           float* __restrict__ num4, int E) {
  const int tid = threadIdx.x;
  const int wv = tid >> 6;
  const int lane = tid & 63;
  const int quad = lane >> 4;
  const int l16 = lane & 15;
  const int ebase = blockIdx.x * TILE_M + wv * 32;

  // Coalesced endpoint loads: lanes 0..31 own edges ebase..ebase+31.
  const int eown = ebase + lane;
  const bool owner = (lane < 32) && (eown < E);
  int s = 0, d = 0;
  if (owner) { s = src[eown]; d = dst[eown]; }

  // Stage this wave's 32 edges of m_ij into MFMA B-fragments.
  // Lane holds B[k = quad*8 + kt*32 + j][n = l16], edge = ebase + et*16 + l16.
  bf16x8 mfrag[2][4];
  #pragma unroll
  for (int et = 0; et < 2; ++et) {
    int e = ebase + et * 16 + l16;
    if (e >= E) e = E - 1;  // clamp (stores are guarded)
    const float* row = m_ij + (size_t)e * MSG + quad * 8;
    #pragma unroll
    for (int kt = 0; kt < 4; ++kt) {
      const float4 v0 = *(const float4*)(row + kt * 32);
      const float4 v1 = *(const float4*)(row + kt * 32 + 4);
      bf16x8 f;
      f[0] = (__bf16)v0.x; f[1] = (__bf16)v0.y;
      f[2] = (__bf16)v0.z; f[3] = (__bf16)v0.w;
      f[4] = (__bf16)v1.x; f[5] = (__bf16)v1.y;
      f[6] = (__bf16)v1.z; f[7] = (__bf16)v1.w;
      mfrag[et][kt] = f;
    }
  }

  // Issue the 6 position gathers now; latency hides under the MFMA loop.
  float sx = 0.f, sy = 0.f, sz = 0.f, gx = 0.f, gy = 0.f, gz = 0.f;
  if (owner) {
    sx = x[3 * s];     sy = x[3 * s + 1]; sz = x[3 * s + 2];
    gx = x[3 * d];     gy = x[3 * d + 1]; gz = x[3 * d + 2];
  }

  // Combined dual-MLP loop. Lane's hidden units: nt*16 + quad*4 + r.
  float pW0 = 0.f, pW1 = 0.f, pA0 = 0.f, pA1 = 0.f;
  #pragma unroll
  for (int nt = 0; nt < 8; ++nt) {
    const size_t ro = (size_t)(nt * 16 + l16) * MSG + quad * 8;
    f32x4 aw0 = {0.f, 0.f, 0.f, 0.f}, aw1 = {0.f, 0.f, 0.f, 0.f};
    f32x4 aa0 = {0.f, 0.f, 0.f, 0.f}, aa1 = {0.f, 0.f, 0.f, 0.f};
    #pragma unroll
    for (int kt = 0; kt < 4; ++kt) {
      const bf16x8 Aw = *(const bf16x8*)(WtW + ro + kt * 32);
      const bf16x8 Aa = *(const bf16x8*)(WtA + ro + kt * 32);
      aw0 = __builtin_amdgcn_mfma_f32_16x16x32_bf16(Aw, mfrag[0][kt], aw0, 0, 0, 0);
      aw1 = __builtin_amdgcn_mfma_f32_16x16x32_bf16(Aw, mfrag[1][kt], aw1, 0, 0, 0);
      aa0 = __builtin_amdgcn_mfma_f32_16x16x32_bf16(Aa, mfrag[0][kt], aa0, 0, 0, 0);
      aa1 = __builtin_amdgcn_mfma_f32_16x16x32_bf16(Aa, mfrag[1][kt], aa1, 0, 0, 0);
    }
    // Fused epilogue for this nt: h = acc + b1; part += silu(h)*W2.
    const f32x4 bwq = *(const f32x4*)(bw1 + nt * 16 + quad * 4);
    const f32x4 wwq = *(const f32x4*)(Ww2 + nt * 16 + quad * 4);
    const f32x4 baq = *(const f32x4*)(ba1 + nt * 16 + quad * 4);
    const f32x4 waq = *(const f32x4*)(Wa2 + nt * 16 + quad * 4);
    #pragma unroll
    for (int r = 0; r < 4; ++r) {
      const float hw0 = aw0[r] + bwq[r];
      const float hw1 = aw1[r] + bwq[r];
      const float ha0 = aa0[r] + baq[r];
      const float ha1 = aa1[r] + baq[r];
      // silu via rcp: saturation-safe (exp(-h)->inf => rcp->0 => silu->0).
      pW0 += (hw0 * wwq[r]) * __builtin_amdgcn_rcpf(1.f + __expf(-hw0));
      pW1 += (hw1 * wwq[r]) * __builtin_amdgcn_rcpf(1.f + __expf(-hw1));
      pA0 += (ha0 * waq[r]) * __builtin_amdgcn_rcpf(1.f + __expf(-ha0));
      pA1 += (ha1 * waq[r]) * __builtin_amdgcn_rcpf(1.f + __expf(-ha1));
    }
  }
  // Sum the 4 quads (disjoint hidden units of the same edge).
  pW0 += __shfl_xor(pW0, 16, 64); pW0 += __shfl_xor(pW0, 32, 64);
  pW1 += __shfl_xor(pW1, 16, 64); pW1 += __shfl_xor(pW1, 32, 64);
  pA0 += __shfl_xor(pA0, 16, 64); pA0 += __shfl_xor(pA0, 32, 64);
  pA1 += __shfl_xor(pA1, 16, 64); pA1 += __shfl_xor(pA1, 32, 64);

  // Fused scatter tail: lanes 0..31 hold edge ebase+lane (p*0 for lanes<16,
  // p*1 for lanes 16..31 -- both index the same l16 column of their tile).
  if (owner) {
    const float vW = ((lane < 16) ? pW0 : pW1) + bw2[0];
    const float vA = ((lane < 16) ? pA0 : pA1) + ba2[0];
    const float a = __expf(vA);
    const float t = vW * a;  // w_raw * a_ij; /a_i deferred to finalize
    const float dx = gx - sx, dy = gy - sy, dz = gz - sz;
    const float nrm = sqrtf(dx * dx + dy * dy + dz * dz);
    const float inv = t * __builtin_amdgcn_rcpf(fmaxf(nrm, 1e-12f));
    float* base = num4 + (size_t)4 * s;
    atomicAdd(base + 0, dx * inv);
    atomicAdd(base + 1, dy * inv);
    atomicAdd(base + 2, dz * inv);
    atomicAdd(base + 3, a);      // a_i segment sum, same 16B slot
  }
}

// ---- Kernel 3: per-node finalize. out = x + num.xyz / num.w (0 if no edges).
__global__ void finalize_kernel(const float* __restrict__ x,
                                const f32x4* __restrict__ num4,
                                float* __restrict__ out, int N) {
  int n = blockIdx.x * blockDim.x + threadIdx.x;
  if (n >= N) return;
  const f32x4 v = num4[n];
  const float inv = (v[3] != 0.f) ? __builtin_amdgcn_rcpf(v[3]) : 0.f;
  out[3 * n + 0] = x[3 * n + 0] + v[0] * inv;
  out[3 * n + 1] = x[3 * n + 1] + v[1] * inv;
  out[3 * n + 2] = x[3 * n + 2] + v[2] * inv;
}

extern "C" void kernel_launch(void* const* d_in, const int* in_sizes, int n_in,
                              void* d_out, int out_size, void* d_ws, size_t ws_size,
                              hipStream_t stream) {
  const float* x    = (const float*)d_in[0];
  const float* m_ij = (const float*)d_in[1];
  const int*   edges = (const int*)d_in[2];
  const float* Ww1 = (const float*)d_in[3];
  const float* bw1 = (const float*)d_in[4];
  const float* Ww2 = (const float*)d_in[5];
  const float* bw2 = (const float*)d_in[6];
  const float* Wa1 = (const float*)d_in[7];
  const float* ba1 = (const float*)d_in[8];
  const float* Wa2 = (const float*)d_in[9];
  const float* ba2 = (const float*)d_in[10];

  const int N = in_sizes[0] / 3;
  const int E = in_sizes[1] / MSG;
  const int* src = edges;        // edges[0] = receiver
  const int* dst = edges + E;    // edges[1] = neighbor

  // Workspace layout (~1.7 MB)
  char* p = (char*)d_ws;
  unsigned short* WtW = (unsigned short*)p; p += (size_t)MSG * MSG * 2;
  unsigned short* WtA = (unsigned short*)p; p += (size_t)MSG * MSG * 2;
  float* num4 = (float*)p; p += (size_t)N * 4 * 4;

  float* out = (float*)d_out;

  hipMemsetAsync(num4, 0, (size_t)N * 4 * 4, stream);
  prep_weights_kernel<<<(MSG * MSG + 255) / 256, 256, 0, stream>>>(Ww1, Wa1, WtW, WtA);
  edge_mlp_fused_kernel<<<(E + TILE_M - 1) / TILE_M, 256, 0, stream>>>(
      m_ij, WtW, WtA, bw1, Ww2, bw2, ba1, Wa2, ba2, src, dst, x, num4, E);
  finalize_kernel<<<(N + 255) / 256, 256, 0, stream>>>(x, (const f32x4*)num4, out, N);
}

// Round 4
// 1420.734 us; speedup vs baseline: 1.2041x; 1.0049x over previous
//
#include <hip/hip_runtime.h>
#include <cmath>

#define MSG 128
#define TILE_M 128

typedef __attribute__((ext_vector_type(8))) __bf16 bf16x8;
typedef __attribute__((ext_vector_type(4))) float f32x4;

__device__ __forceinline__ unsigned short f2bf(float f) {
  union { float f; unsigned u; } v; v.f = f;
  unsigned r = v.u + 0x7FFFu + ((v.u >> 16) & 1u);  // round-to-nearest-even
  return (unsigned short)(r >> 16);
}

// ---- Kernel 1: convert + transpose both hidden-layer weight matrices to bf16.
// Wt[n][k] = W1[k][n] so MFMA fragments (contiguous in k) are vector loads.
__global__ void prep_weights_kernel(const float* __restrict__ Ww1,
                                    const float* __restrict__ Wa1,
                                    unsigned short* __restrict__ WtW,
                                    unsigned short* __restrict__ WtA) {
  int idx = blockIdx.x * blockDim.x + threadIdx.x;
  if (idx < MSG * MSG) {
    int k = idx >> 7;
    int n = idx & 127;
    WtW[n * MSG + k] = f2bf(Ww1[idx]);
    WtA[n * MSG + k] = f2bf(Wa1[idx]);
  }
}

// ---- Kernel 2: fully fused edge pass (dual MLP + scatter).
// Operand-swapped MFMA: A = weights (rows = hidden units), B = m_ij (cols =
// edges), so D cols are edges. Latency discipline (the round-3 lesson:
// VGPR=40 => serialized loads => ~22K stall cycles/wave):
//   - staging: ALL 16 m_ij dwordx4 loads issued into raw[16] before any
//     convert -> one HBM exposure per wave instead of eight.
//   - weights + epilogue constants: double-buffered one nt ahead; the ~460
//     cycles of MFMA+silu per nt cover the ~250-cycle L2 prefetch.
// Scatter identity: sum_e (w_e*a_e/a_i[s])*dir_e = (1/a_i[s]) * sum_e
// w_e*a_e*dir_e, so /a_i is deferred to finalize; all 4 atomics land in one
// 16B slot of num4[s].
__global__ __launch_bounds__(256, 3)
void edge_mlp_fused_kernel(const float* __restrict__ m_ij,
                           const unsigned short* __restrict__ WtW,
                           const unsigned short* __restrict__ WtA,
                           const float* __restrict__ bw1, const float* __restrict__ Ww2,
                           const float* __restrict__ bw2,
                           const float* __restrict__ ba1, const float* __restrict__ Wa2,
                           const float* __restrict__ ba2,
                           const int* __restrict__ src,
                           const int* __restrict__ dst,
                           const float* __restrict__ x,
                           float* __restrict__ num4, int E) {
  const int tid = threadIdx.x;
  const int wv = tid >> 6;
  const int lane = tid & 63;
  const int quad = lane >> 4;
  const int l16 = lane & 15;
  const int ebase = blockIdx.x * TILE_M + wv * 32;

  // Coalesced endpoint loads: lanes 0..31 own edges ebase..ebase+31.
  const int eown = ebase + lane;
  const bool owner = (lane < 32) && (eown < E);
  int s = 0, d = 0;
  if (owner) { s = src[eown]; d = dst[eown]; }

  // ---- Phase 1: issue ALL staging loads (16 dwordx4, static raw[] indices).
  int e0 = ebase + l16;       if (e0 >= E) e0 = E - 1;
  int e1 = ebase + 16 + l16;  if (e1 >= E) e1 = E - 1;
  const float* row0 = m_ij + (size_t)e0 * MSG + quad * 8;
  const float* row1 = m_ij + (size_t)e1 * MSG + quad * 8;
  float4 raw[16];
  #pragma unroll
  for (int kt = 0; kt < 4; ++kt) {
    raw[kt * 2 + 0] = *(const float4*)(row0 + kt * 32);
    raw[kt * 2 + 1] = *(const float4*)(row0 + kt * 32 + 4);
    raw[8 + kt * 2 + 0] = *(const float4*)(row1 + kt * 32);
    raw[8 + kt * 2 + 1] = *(const float4*)(row1 + kt * 32 + 4);
  }
  // Position gathers issued up-front too; latency hides under the MFMA loop.
  float sx = 0.f, sy = 0.f, sz = 0.f, gx = 0.f, gy = 0.f, gz = 0.f;
  if (owner) {
    sx = x[3 * s];     sy = x[3 * s + 1]; sz = x[3 * s + 2];
    gx = x[3 * d];     gy = x[3 * d + 1]; gz = x[3 * d + 2];
  }

  // ---- Phase 2: convert to MFMA B-fragments.
  // Lane holds B[k = quad*8 + kt*32 + j][n = l16], edge = ebase + et*16 + l16.
  bf16x8 mfrag[2][4];
  #pragma unroll
  for (int et = 0; et < 2; ++et) {
    #pragma unroll
    for (int kt = 0; kt < 4; ++kt) {
      const float4 v0 = raw[et * 8 + kt * 2 + 0];
      const float4 v1 = raw[et * 8 + kt * 2 + 1];
      bf16x8 f;
      f[0] = (__bf16)v0.x; f[1] = (__bf16)v0.y;
      f[2] = (__bf16)v0.z; f[3] = (__bf16)v0.w;
      f[4] = (__bf16)v1.x; f[5] = (__bf16)v1.y;
      f[6] = (__bf16)v1.z; f[7] = (__bf16)v1.w;
      mfrag[et][kt] = f;
    }
  }

  // ---- Main loop: dual MLP, weights + constants prefetched one nt ahead.
  bf16x8 wb[2][2][4];  // [buf][matrix W/A][kt]
  f32x4 cb[2][4];      // [buf][bw1,Ww2,ba1,Wa2]
  {
    const size_t ro = (size_t)l16 * MSG + quad * 8;
    #pragma unroll
    for (int kt = 0; kt < 4; ++kt) {
      wb[0][0][kt] = *(const bf16x8*)(WtW + ro + kt * 32);
      wb[0][1][kt] = *(const bf16x8*)(WtA + ro + kt * 32);
    }
    const int co = quad * 4;
    cb[0][0] = *(const f32x4*)(bw1 + co);
    cb[0][1] = *(const f32x4*)(Ww2 + co);
    cb[0][2] = *(const f32x4*)(ba1 + co);
    cb[0][3] = *(const f32x4*)(Wa2 + co);
  }

  float pW0 = 0.f, pW1 = 0.f, pA0 = 0.f, pA1 = 0.f;
  #pragma unroll
  for (int nt = 0; nt < 8; ++nt) {
    const int cur = nt & 1, nxt = cur ^ 1;
    if (nt < 7) {  // prefetch nt+1 (static indices after unroll)
      const size_t ro = (size_t)((nt + 1) * 16 + l16) * MSG + quad * 8;
      #pragma unroll
      for (int kt = 0; kt < 4; ++kt) {
        wb[nxt][0][kt] = *(const bf16x8*)(WtW + ro + kt * 32);
        wb[nxt][1][kt] = *(const bf16x8*)(WtA + ro + kt * 32);
      }
      const int co = (nt + 1) * 16 + quad * 4;
      cb[nxt][0] = *(const f32x4*)(bw1 + co);
      cb[nxt][1] = *(const f32x4*)(Ww2 + co);
      cb[nxt][2] = *(const f32x4*)(ba1 + co);
      cb[nxt][3] = *(const f32x4*)(Wa2 + co);
    }
    f32x4 aw0 = {0.f, 0.f, 0.f, 0.f}, aw1 = {0.f, 0.f, 0.f, 0.f};
    f32x4 aa0 = {0.f, 0.f, 0.f, 0.f}, aa1 = {0.f, 0.f, 0.f, 0.f};
    #pragma unroll
    for (int kt = 0; kt < 4; ++kt) {
      aw0 = __builtin_amdgcn_mfma_f32_16x16x32_bf16(wb[cur][0][kt], mfrag[0][kt], aw0, 0, 0, 0);
      aw1 = __builtin_amdgcn_mfma_f32_16x16x32_bf16(wb[cur][0][kt], mfrag[1][kt], aw1, 0, 0, 0);
      aa0 = __builtin_amdgcn_mfma_f32_16x16x32_bf16(wb[cur][1][kt], mfrag[0][kt], aa0, 0, 0, 0);
      aa1 = __builtin_amdgcn_mfma_f32_16x16x32_bf16(wb[cur][1][kt], mfrag[1][kt], aa1, 0, 0, 0);
    }
    // Fused epilogue for this nt: h = acc + b1; part += silu(h)*W2.
    #pragma unroll
    for (int r = 0; r < 4; ++r) {
      const float hw0 = aw0[r] + cb[cur][0][r];
      const float hw1 = aw1[r] + cb[cur][0][r];
      const float ha0 = aa0[r] + cb[cur][2][r];
      const float ha1 = aa1[r] + cb[cur][2][r];
      // silu via rcp: saturation-safe (exp(-h)->inf => rcp->0 => silu->0).
      pW0 += (hw0 * cb[cur][1][r]) * __builtin_amdgcn_rcpf(1.f + __expf(-hw0));
      pW1 += (hw1 * cb[cur][1][r]) * __builtin_amdgcn_rcpf(1.f + __expf(-hw1));
      pA0 += (ha0 * cb[cur][3][r]) * __builtin_amdgcn_rcpf(1.f + __expf(-ha0));
      pA1 += (ha1 * cb[cur][3][r]) * __builtin_amdgcn_rcpf(1.f + __expf(-ha1));
    }
  }
  // Sum the 4 quads (disjoint hidden units of the same edge).
  pW0 += __shfl_xor(pW0, 16, 64); pW0 += __shfl_xor(pW0, 32, 64);
  pW1 += __shfl_xor(pW1, 16, 64); pW1 += __shfl_xor(pW1, 32, 64);
  pA0 += __shfl_xor(pA0, 16, 64); pA0 += __shfl_xor(pA0, 32, 64);
  pA1 += __shfl_xor(pA1, 16, 64); pA1 += __shfl_xor(pA1, 32, 64);

  // Fused scatter tail: lanes 0..31 hold edge ebase+lane.
  if (owner) {
    const float vW = ((lane < 16) ? pW0 : pW1) + bw2[0];
    const float vA = ((lane < 16) ? pA0 : pA1) + ba2[0];
    const float a = __expf(vA);
    const float t = vW * a;  // w_raw * a_ij; /a_i deferred to finalize
    const float dx = gx - sx, dy = gy - sy, dz = gz - sz;
    const float nrm = sqrtf(dx * dx + dy * dy + dz * dz);
    const float inv = t * __builtin_amdgcn_rcpf(fmaxf(nrm, 1e-12f));
    float* base = num4 + (size_t)4 * s;
    atomicAdd(base + 0, dx * inv);
    atomicAdd(base + 1, dy * inv);
    atomicAdd(base + 2, dz * inv);
    atomicAdd(base + 3, a);      // a_i segment sum, same 16B slot
  }
}

// ---- Kernel 3: per-node finalize. out = x + num.xyz / num.w (0 if no edges).
__global__ void finalize_kernel(const float* __restrict__ x,
                                const f32x4* __restrict__ num4,
                                float* __restrict__ out, int N) {
  int n = blockIdx.x * blockDim.x + threadIdx.x;
  if (n >= N) return;
  const f32x4 v = num4[n];
  const float inv = (v[3] != 0.f) ? __builtin_amdgcn_rcpf(v[3]) : 0.f;
  out[3 * n + 0] = x[3 * n + 0] + v[0] * inv;
  out[3 * n + 1] = x[3 * n + 1] + v[1] * inv;
  out[3 * n + 2] = x[3 * n + 2] + v[2] * inv;
}

extern "C" void kernel_launch(void* const* d_in, const int* in_sizes, int n_in,
                              void* d_out, int out_size, void* d_ws, size_t ws_size,
                              hipStream_t stream) {
  const float* x    = (const float*)d_in[0];
  const float* m_ij = (const float*)d_in[1];
  const int*   edges = (const int*)d_in[2];
  const float* Ww1 = (const float*)d_in[3];
  const float* bw1 = (const float*)d_in[4];
  const float* Ww2 = (const float*)d_in[5];
  const float* bw2 = (const float*)d_in[6];
  const float* Wa1 = (const float*)d_in[7];
  const float* ba1 = (const float*)d_in[8];
  const float* Wa2 = (const float*)d_in[9];
  const float* ba2 = (const float*)d_in[10];

  const int N = in_sizes[0] / 3;
  const int E = in_sizes[1] / MSG;
  const int* src = edges;        // edges[0] = receiver
  const int* dst = edges + E;    // edges[1] = neighbor

  // Workspace layout (~1.7 MB)
  char* p = (char*)d_ws;
  unsigned short* WtW = (unsigned short*)p; p += (size_t)MSG * MSG * 2;
  unsigned short* WtA = (unsigned short*)p; p += (size_t)MSG * MSG * 2;
  float* num4 = (float*)p; p += (size_t)N * 4 * 4;

  float* out = (float*)d_out;

  hipMemsetAsync(num4, 0, (size_t)N * 4 * 4, stream);
  prep_weights_kernel<<<(MSG * MSG + 255) / 256, 256, 0, stream>>>(Ww1, Wa1, WtW, WtA);
  edge_mlp_fused_kernel<<<(E + TILE_M - 1) / TILE_M, 256, 0, stream>>>(
      m_ij, WtW, WtA, bw1, Ww2, bw2, ba1, Wa2, ba2, src, dst, x, num4, E);
  finalize_kernel<<<(N + 255) / 256, 256, 0, stream>>>(x, (const f32x4*)num4, out, N);
}

// Round 5
// 1237.913 us; speedup vs baseline: 1.3819x; 1.1477x over previous
//
#include <hip/hip_runtime.h>
#include <cmath>

#define MSG 128
#define TILE 64      // edges per LDS tile
#define TPB 256
#define NB_MAX 512   // 2 blocks/CU

typedef __attribute__((ext_vector_type(8))) __bf16 bf16x8;
typedef __attribute__((ext_vector_type(4))) float f32x4;

__device__ __forceinline__ unsigned short f2bf(float f) {
  union { float f; unsigned u; } v; v.f = f;
  unsigned r = v.u + 0x7FFFu + ((v.u >> 16) & 1u);  // round-to-nearest-even
  return (unsigned short)(r >> 16);
}

// ---- Kernel 1: convert + transpose both hidden-layer weight matrices to bf16.
__global__ void prep_weights_kernel(const float* __restrict__ Ww1,
                                    const float* __restrict__ Wa1,
                                    unsigned short* __restrict__ WtW,
                                    unsigned short* __restrict__ WtA) {
  int idx = blockIdx.x * blockDim.x + threadIdx.x;
  if (idx < MSG * MSG) {
    int k = idx >> 7;
    int n = idx & 127;
    WtW[n * MSG + k] = f2bf(Ww1[idx]);
    WtA[n * MSG + k] = f2bf(Wa1[idx]);
  }
}

__device__ __forceinline__ void gload_lds16(const float* g, float* l) {
  __builtin_amdgcn_global_load_lds(
      (const __attribute__((address_space(1))) void*)g,
      (__attribute__((address_space(3))) void*)l, 16, 0, 0);
}

// ---- Kernel 2: persistent 2-phase pipelined edge pass.
// Round-4 lesson: compiler serializes VGPR-destined loads (VGPR=68 proved the
// register pipeline was never realized) -> every wave is a ~70K-cycle latency
// chain. Fix: weights permanent in registers (wave w owns units [32w,32w+32)),
// m_ij streamed via global_load_lds (no dest regs, fire-and-forget) into
// double-buffered XOR-swizzled LDS tiles, ONE counted s_waitcnt vmcnt(4) per
// tile (atomics left in flight). Cross-wave unit-partials reduced via 2KB LDS.
__global__ __launch_bounds__(TPB, 2)
void edge_mlp_pipe_kernel(const float* __restrict__ m_ij,
                          const unsigned short* __restrict__ WtW,
                          const unsigned short* __restrict__ WtA,
                          const float* __restrict__ bw1, const float* __restrict__ Ww2,
                          const float* __restrict__ bw2,
                          const float* __restrict__ ba1, const float* __restrict__ Wa2,
                          const float* __restrict__ ba2,
                          const int* __restrict__ src,
                          const int* __restrict__ dst,
                          const float* __restrict__ x,
                          float* __restrict__ num4, int E, int ntiles) {
  __shared__ __align__(16) float buf[2][TILE * MSG];  // 2 x 32KB, swizzled rows
  __shared__ float plds[2][4][TILE];                  // [mlp][wave][edge] 2KB

  const int tid = threadIdx.x;
  const int w = tid >> 6;
  const int lane = tid & 63;
  const int quad = lane >> 4;
  const int l16 = lane & 15;

  // --- Persistent weights: wave w owns hidden units [32w, 32w+32).
  // A-frag: A[m = unit16 + l16][k = quad*8 + kt*32 + j].
  bf16x8 wf[2][2][4];      // [nt][mat W/A][kt]
  f32x4 c1[2][2], c2[2][2];  // [nt][mat]: layer-1 bias, layer-2 weight @quad*4
  #pragma unroll
  for (int nt = 0; nt < 2; ++nt) {
    const int unit16 = w * 32 + nt * 16;
    const size_t ro = (size_t)(unit16 + l16) * MSG + quad * 8;
    #pragma unroll
    for (int kt = 0; kt < 4; ++kt) {
      wf[nt][0][kt] = *(const bf16x8*)(WtW + ro + kt * 32);
      wf[nt][1][kt] = *(const bf16x8*)(WtA + ro + kt * 32);
    }
    const int co = unit16 + quad * 4;
    c1[nt][0] = *(const f32x4*)(bw1 + co);
    c2[nt][0] = *(const f32x4*)(Ww2 + co);
    c1[nt][1] = *(const f32x4*)(ba1 + co);
    c2[nt][1] = *(const f32x4*)(Wa2 + co);
  }
  const float bw2s = bw2[0], ba2s = ba2[0];

  // Stage one 64x128 fp32 tile into buf[bsel]. LDS dest is linear (chunk*16B,
  // = wave-uniform base + lane*16 by construction); the XOR swizzle
  // (byte ^= (row&7)<<4, involution, row-preserving) is applied to the GLOBAL
  // source address so LDS content is swizzled (T21: both-sides-or-neither).
  auto stage = [&](int tile, int bsel) {
    #pragma unroll
    for (int i = 0; i < 8; ++i) {
      const int chunk = i * TPB + tid;        // 0..2047
      const int db = chunk * 16;              // dest byte in [0, 32768)
      const int row = db >> 9;                // tile row (512B rows)
      const int col = db & 511;
      const int scol = col ^ ((row & 7) << 4);
      int grow = tile * TILE + row;
      if (grow >= E) grow = E - 1;            // clamp (stores guarded later)
      const float* g = m_ij + (size_t)grow * MSG + (scol >> 2);
      gload_lds16(g, &buf[bsel][0] + (db >> 2));
    }
  };

  int tt = blockIdx.x;
  if (tt < ntiles) stage(tt, 0);
  asm volatile("s_waitcnt vmcnt(0)" ::: "memory");
  __builtin_amdgcn_s_barrier();
  int cur = 0;

  for (; tt < ntiles; tt += gridDim.x) {
    const int nxt = tt + (int)gridDim.x;
    if (nxt < ntiles) stage(nxt, cur ^ 1);    // fire-and-forget

    // Prefetch finalize operands for THIS tile (lanes quad==0 own 16 edges).
    const int eL = w * 16 + l16;
    const int ge = tt * TILE + eL;
    const bool fown = (quad == 0) && (ge < E);
    int sN = 0, dN = 0;
    float sx = 0.f, sy = 0.f, sz = 0.f, gx = 0.f, gy = 0.f, gz = 0.f;
    if (fown) { sN = src[ge]; dN = dst[ge]; }
    if (fown) {
      sx = x[3 * sN]; sy = x[3 * sN + 1]; sz = x[3 * sN + 2];
      gx = x[3 * dN]; gy = x[3 * dN + 1]; gz = x[3 * dN + 2];
    }

    // Compute: 4 edge sub-tiles of 16; B[k][n=edge] from swizzled LDS.
    #pragma unroll
    for (int et = 0; et < 4; ++et) {
      const int row = et * 16 + l16;
      const int rbase = row * MSG;            // float index
      const int xorf = (row & 7) << 2;        // float-index xor (= byte<<4)
      bf16x8 bf[4];
      #pragma unroll
      for (int kt = 0; kt < 4; ++kt) {
        const int c0 = quad * 8 + kt * 32;
        const f32x4 v0 = *(const f32x4*)(&buf[cur][rbase + (c0 ^ xorf)]);
        const f32x4 v1 = *(const f32x4*)(&buf[cur][rbase + ((c0 + 4) ^ xorf)]);
        bf16x8 f;
        f[0] = (__bf16)v0.x; f[1] = (__bf16)v0.y;
        f[2] = (__bf16)v0.z; f[3] = (__bf16)v0.w;
        f[4] = (__bf16)v1.x; f[5] = (__bf16)v1.y;
        f[6] = (__bf16)v1.z; f[7] = (__bf16)v1.w;
        bf[kt] = f;
      }
      f32x4 acc[2][2];
      #pragma unroll
      for (int nt = 0; nt < 2; ++nt) {
        acc[nt][0] = {0.f, 0.f, 0.f, 0.f};
        acc[nt][1] = {0.f, 0.f, 0.f, 0.f};
      }
      #pragma unroll
      for (int kt = 0; kt < 4; ++kt) {
        #pragma unroll
        for (int nt = 0; nt < 2; ++nt) {
          acc[nt][0] = __builtin_amdgcn_mfma_f32_16x16x32_bf16(wf[nt][0][kt], bf[kt], acc[nt][0], 0, 0, 0);
          acc[nt][1] = __builtin_amdgcn_mfma_f32_16x16x32_bf16(wf[nt][1][kt], bf[kt], acc[nt][1], 0, 0, 0);
        }
      }
      // Fused epilogue over this wave's 8 units/lane: silu(h)*W2 partials.
      float pW = 0.f, pA = 0.f;
      #pragma unroll
      for (int nt = 0; nt < 2; ++nt) {
        #pragma unroll
        for (int r = 0; r < 4; ++r) {
          const float hw = acc[nt][0][r] + c1[nt][0][r];
          const float ha = acc[nt][1][r] + c1[nt][1][r];
          pW += (hw * c2[nt][0][r]) * __builtin_amdgcn_rcpf(1.f + __expf(-hw));
          pA += (ha * c2[nt][1][r]) * __builtin_amdgcn_rcpf(1.f + __expf(-ha));
        }
      }
      pW += __shfl_xor(pW, 16, 64); pW += __shfl_xor(pW, 32, 64);
      pA += __shfl_xor(pA, 16, 64); pA += __shfl_xor(pA, 32, 64);
      if (quad == 0) {
        plds[0][w][et * 16 + l16] = pW;
        plds[1][w][et * 16 + l16] = pA;
      }
    }

    // Barrier A: partials visible to all waves.
    asm volatile("s_waitcnt lgkmcnt(0)" ::: "memory");
    __builtin_amdgcn_s_barrier();

    // Finalize: cross-wave sum + scatter (4 atomics into one 16B slot).
    if (fown) {
      const float sW = plds[0][0][eL] + plds[0][1][eL] + plds[0][2][eL] + plds[0][3][eL];
      const float sA = plds[1][0][eL] + plds[1][1][eL] + plds[1][2][eL] + plds[1][3][eL];
      const float a = __expf(sA + ba2s);
      const float t = (sW + bw2s) * a;  // w*a; /a_i deferred to finalize kernel
      const float dx = gx - sx, dy = gy - sy, dz = gz - sz;
      const float nrm = sqrtf(dx * dx + dy * dy + dz * dz);
      const float inv = t * __builtin_amdgcn_rcpf(fmaxf(nrm, 1e-12f));
      float* basep = num4 + (size_t)4 * sN;
      atomicAdd(basep + 0, dx * inv);
      atomicAdd(basep + 1, dy * inv);
      atomicAdd(basep + 2, dz * inv);
      atomicAdd(basep + 3, a);
    }

    // Barrier B: next tile's staging landed. vmcnt(4) leaves the 4 just-issued
    // atomics outstanding (they need no ordering); plds reads already consumed.
    asm volatile("s_waitcnt vmcnt(4) lgkmcnt(0)" ::: "memory");
    __builtin_amdgcn_s_barrier();
    cur ^= 1;
  }
}

// ---- Kernel 3: per-node finalize. out = x + num.xyz / num.w (0 if no edges).
__global__ void finalize_kernel(const float* __restrict__ x,
                                const f32x4* __restrict__ num4,
                                float* __restrict__ out, int N) {
  int n = blockIdx.x * blockDim.x + threadIdx.x;
  if (n >= N) return;
  const f32x4 v = num4[n];
  const float inv = (v[3] != 0.f) ? __builtin_amdgcn_rcpf(v[3]) : 0.f;
  out[3 * n + 0] = x[3 * n + 0] + v[0] * inv;
  out[3 * n + 1] = x[3 * n + 1] + v[1] * inv;
  out[3 * n + 2] = x[3 * n + 2] + v[2] * inv;
}

extern "C" void kernel_launch(void* const* d_in, const int* in_sizes, int n_in,
                              void* d_out, int out_size, void* d_ws, size_t ws_size,
                              hipStream_t stream) {
  const float* x    = (const float*)d_in[0];
  const float* m_ij = (const float*)d_in[1];
  const int*   edges = (const int*)d_in[2];
  const float* Ww1 = (const float*)d_in[3];
  const float* bw1 = (const float*)d_in[4];
  const float* Ww2 = (const float*)d_in[5];
  const float* bw2 = (const float*)d_in[6];
  const float* Wa1 = (const float*)d_in[7];
  const float* ba1 = (const float*)d_in[8];
  const float* Wa2 = (const float*)d_in[9];
  const float* ba2 = (const float*)d_in[10];

  const int N = in_sizes[0] / 3;
  const int E = in_sizes[1] / MSG;
  const int* src = edges;        // edges[0] = receiver
  const int* dst = edges + E;    // edges[1] = neighbor

  // Workspace layout (~1.7 MB)
  char* p = (char*)d_ws;
  unsigned short* WtW = (unsigned short*)p; p += (size_t)MSG * MSG * 2;
  unsigned short* WtA = (unsigned short*)p; p += (size_t)MSG * MSG * 2;
  float* num4 = (float*)p; p += (size_t)N * 4 * 4;

  float* out = (float*)d_out;

  const int ntiles = (E + TILE - 1) / TILE;
  const int nb = ntiles < NB_MAX ? ntiles : NB_MAX;

  hipMemsetAsync(num4, 0, (size_t)N * 4 * 4, stream);
  prep_weights_kernel<<<(MSG * MSG + 255) / 256, 256, 0, stream>>>(Ww1, Wa1, WtW, WtA);
  edge_mlp_pipe_kernel<<<nb, TPB, 0, stream>>>(
      m_ij, WtW, WtA, bw1, Ww2, bw2, ba1, Wa2, ba2, src, dst, x, num4, E, ntiles);
  finalize_kernel<<<(N + 255) / 256, 256, 0, stream>>>(x, (const f32x4*)num4, out, N);
}

// Round 6
// 1232.241 us; speedup vs baseline: 1.3883x; 1.0046x over previous
//
#include <hip/hip_runtime.h>
#include <cmath>

#define MSG 128
#define TILE 64      // edges per LDS tile
#define TPB 512      // 8 waves; each wave owns 16 hidden units
#define NB_MAX 512   // 2 blocks/CU

typedef __attribute__((ext_vector_type(8))) __bf16 bf16x8;
typedef __attribute__((ext_vector_type(4))) float f32x4;

__device__ __forceinline__ unsigned short f2bf(float f) {
  union { float f; unsigned u; } v; v.f = f;
  unsigned r = v.u + 0x7FFFu + ((v.u >> 16) & 1u);  // round-to-nearest-even
  return (unsigned short)(r >> 16);
}

// ---- Kernel 1: convert + transpose both hidden-layer weight matrices to bf16.
__global__ void prep_weights_kernel(const float* __restrict__ Ww1,
                                    const float* __restrict__ Wa1,
                                    unsigned short* __restrict__ WtW,
                                    unsigned short* __restrict__ WtA) {
  int idx = blockIdx.x * blockDim.x + threadIdx.x;
  if (idx < MSG * MSG) {
    int k = idx >> 7;
    int n = idx & 127;
    WtW[n * MSG + k] = f2bf(Ww1[idx]);
    WtA[n * MSG + k] = f2bf(Wa1[idx]);
  }
}

__device__ __forceinline__ void gload_lds16(const float* g, float* l) {
  __builtin_amdgcn_global_load_lds(
      (const __attribute__((address_space(1))) void*)g,
      (__attribute__((address_space(3))) void*)l, 16, 0, 0);
}

// ---- Kernel 2: persistent 2-phase pipelined edge pass (8-wave blocks).
// Structure proven in round 5 (global_load_lds + double-buffer + counted
// vmcnt): this round widens to 8 waves/block so 4 waves/SIMD are co-resident
// (was 2) -- barrier-drain and HBM-delivery stalls in one block now hide
// under the other block's compute. Each wave owns 16 hidden units (1 MFMA
// row-tile), halving per-wave MFMA + transcendental chains.
__global__ __launch_bounds__(TPB, 2)
void edge_mlp_pipe_kernel(const float* __restrict__ m_ij,
                          const unsigned short* __restrict__ WtW,
                          const unsigned short* __restrict__ WtA,
                          const float* __restrict__ bw1, const float* __restrict__ Ww2,
                          const float* __restrict__ bw2,
                          const float* __restrict__ ba1, const float* __restrict__ Wa2,
                          const float* __restrict__ ba2,
                          const int* __restrict__ src,
                          const int* __restrict__ dst,
                          const float* __restrict__ x,
                          float* __restrict__ num4, int E, int ntiles) {
  __shared__ __align__(16) float buf[2][TILE * MSG];  // 2 x 32KB, swizzled rows
  __shared__ float plds[2][8][TILE];                  // [mlp][wave][edge] 4KB

  const int tid = threadIdx.x;
  const int w = tid >> 6;
  const int lane = tid & 63;
  const int quad = lane >> 4;
  const int l16 = lane & 15;

  // --- Persistent weights: wave w owns hidden units [16w, 16w+16).
  // A-frag: A[m = 16w + l16][k = quad*8 + kt*32 + j].
  bf16x8 wf[2][4];   // [mat W/A][kt]
  f32x4 c1[2], c2[2];  // [mat]: layer-1 bias, layer-2 weight @ 16w + quad*4
  {
    const int unit16 = w * 16;
    const size_t ro = (size_t)(unit16 + l16) * MSG + quad * 8;
    #pragma unroll
    for (int kt = 0; kt < 4; ++kt) {
      wf[0][kt] = *(const bf16x8*)(WtW + ro + kt * 32);
      wf[1][kt] = *(const bf16x8*)(WtA + ro + kt * 32);
    }
    const int co = unit16 + quad * 4;
    c1[0] = *(const f32x4*)(bw1 + co);
    c2[0] = *(const f32x4*)(Ww2 + co);
    c1[1] = *(const f32x4*)(ba1 + co);
    c2[1] = *(const f32x4*)(Wa2 + co);
  }
  const float bw2s = bw2[0], ba2s = ba2[0];

  // Stage one 64x128 fp32 tile into buf[bsel]. LDS dest is linear; the XOR
  // swizzle (byte ^= (row&7)<<4, involution, row-preserving) is applied to the
  // GLOBAL source address (T21: both-sides-or-neither).
  auto stage = [&](int tile, int bsel) {
    #pragma unroll
    for (int i = 0; i < 4; ++i) {
      const int chunk = i * TPB + tid;        // 0..2047
      const int db = chunk * 16;              // dest byte in [0, 32768)
      const int row = db >> 9;                // tile row (512B rows)
      const int col = db & 511;
      const int scol = col ^ ((row & 7) << 4);
      int grow = tile * TILE + row;
      if (grow >= E) grow = E - 1;            // clamp (stores guarded later)
      const float* g = m_ij + (size_t)grow * MSG + (scol >> 2);
      gload_lds16(g, &buf[bsel][0] + (db >> 2));
    }
  };

  int tt = blockIdx.x;
  if (tt < ntiles) stage(tt, 0);
  asm volatile("s_waitcnt vmcnt(0)" ::: "memory");
  __builtin_amdgcn_s_barrier();
  int cur = 0;

  for (; tt < ntiles; tt += gridDim.x) {
    const int nxt = tt + (int)gridDim.x;
    if (nxt < ntiles) stage(nxt, cur ^ 1);    // fire-and-forget

    // Prefetch finalize operands for THIS tile (waves 0..3, quad==0 lanes own
    // 16 edges each -> 64 edges).
    const int eL = w * 16 + l16;
    const int ge = tt * TILE + eL;
    const bool fown = (quad == 0) && (w < 4) && (ge < E);
    int sN = 0, dN = 0;
    float sx = 0.f, sy = 0.f, sz = 0.f, gx = 0.f, gy = 0.f, gz = 0.f;
    if (fown) {
      sN = src[ge]; dN = dst[ge];
      sx = x[3 * sN]; sy = x[3 * sN + 1]; sz = x[3 * sN + 2];
      gx = x[3 * dN]; gy = x[3 * dN + 1]; gz = x[3 * dN + 2];
    }

    // Compute: 4 edge sub-tiles of 16; B[k][n=edge] from swizzled LDS.
    #pragma unroll
    for (int et = 0; et < 4; ++et) {
      const int row = et * 16 + l16;
      const int rbase = row * MSG;            // float index
      const int xorf = (row & 7) << 2;        // float-index xor (= byte<<4)
      bf16x8 bf[4];
      #pragma unroll
      for (int kt = 0; kt < 4; ++kt) {
        const int c0 = quad * 8 + kt * 32;
        const f32x4 v0 = *(const f32x4*)(&buf[cur][rbase + (c0 ^ xorf)]);
        const f32x4 v1 = *(const f32x4*)(&buf[cur][rbase + ((c0 + 4) ^ xorf)]);
        bf16x8 f;
        f[0] = (__bf16)v0.x; f[1] = (__bf16)v0.y;
        f[2] = (__bf16)v0.z; f[3] = (__bf16)v0.w;
        f[4] = (__bf16)v1.x; f[5] = (__bf16)v1.y;
        f[6] = (__bf16)v1.z; f[7] = (__bf16)v1.w;
        bf[kt] = f;
      }
      f32x4 accW = {0.f, 0.f, 0.f, 0.f};
      f32x4 accA = {0.f, 0.f, 0.f, 0.f};
      #pragma unroll
      for (int kt = 0; kt < 4; ++kt) {
        accW = __builtin_amdgcn_mfma_f32_16x16x32_bf16(wf[0][kt], bf[kt], accW, 0, 0, 0);
        accA = __builtin_amdgcn_mfma_f32_16x16x32_bf16(wf[1][kt], bf[kt], accA, 0, 0, 0);
      }
      // Fused epilogue over this wave's 4 units/lane: silu(h)*W2 partials.
      float pW = 0.f, pA = 0.f;
      #pragma unroll
      for (int r = 0; r < 4; ++r) {
        const float hw = accW[r] + c1[0][r];
        const float ha = accA[r] + c1[1][r];
        // silu via rcp: saturation-safe (exp(-h)->inf => rcp->0 => silu->0).
        pW += (hw * c2[0][r]) * __builtin_amdgcn_rcpf(1.f + __expf(-hw));
        pA += (ha * c2[1][r]) * __builtin_amdgcn_rcpf(1.f + __expf(-ha));
      }
      pW += __shfl_xor(pW, 16, 64); pW += __shfl_xor(pW, 32, 64);
      pA += __shfl_xor(pA, 16, 64); pA += __shfl_xor(pA, 32, 64);
      if (quad == 0) {
        plds[0][w][et * 16 + l16] = pW;
        plds[1][w][et * 16 + l16] = pA;
      }
    }

    // Barrier A: partials visible to all waves.
    asm volatile("s_waitcnt lgkmcnt(0)" ::: "memory");
    __builtin_amdgcn_s_barrier();

    // Finalize: cross-wave sum (8 waves) + scatter (4 atomics, one 16B slot).
    if (fown) {
      float sW = 0.f, sA = 0.f;
      #pragma unroll
      for (int ww = 0; ww < 8; ++ww) {
        sW += plds[0][ww][eL];
        sA += plds[1][ww][eL];
      }
      const float a = __expf(sA + ba2s);
      const float t = (sW + bw2s) * a;  // w*a; /a_i deferred to finalize kernel
      const float dx = gx - sx, dy = gy - sy, dz = gz - sz;
      const float nrm = sqrtf(dx * dx + dy * dy + dz * dz);
      const float inv = t * __builtin_amdgcn_rcpf(fmaxf(nrm, 1e-12f));
      float* basep = num4 + (size_t)4 * sN;
      atomicAdd(basep + 0, dx * inv);
      atomicAdd(basep + 1, dy * inv);
      atomicAdd(basep + 2, dz * inv);
      atomicAdd(basep + 3, a);
    }

    // Barrier B: next tile's staging landed. vmcnt(4) leaves the 4 just-issued
    // atomics outstanding; plds reads already consumed (lgkmcnt drains them).
    asm volatile("s_waitcnt vmcnt(4) lgkmcnt(0)" ::: "memory");
    __builtin_amdgcn_s_barrier();
    cur ^= 1;
  }
}

// ---- Kernel 3: per-node finalize. out = x + num.xyz / num.w (0 if no edges).
__global__ void finalize_kernel(const float* __restrict__ x,
                                const f32x4* __restrict__ num4,
                                float* __restrict__ out, int N) {
  int n = blockIdx.x * blockDim.x + threadIdx.x;
  if (n >= N) return;
  const f32x4 v = num4[n];
  const float inv = (v[3] != 0.f) ? __builtin_amdgcn_rcpf(v[3]) : 0.f;
  out[3 * n + 0] = x[3 * n + 0] + v[0] * inv;
  out[3 * n + 1] = x[3 * n + 1] + v[1] * inv;
  out[3 * n + 2] = x[3 * n + 2] + v[2] * inv;
}

extern "C" void kernel_launch(void* const* d_in, const int* in_sizes, int n_in,
                              void* d_out, int out_size, void* d_ws, size_t ws_size,
                              hipStream_t stream) {
  const float* x    = (const float*)d_in[0];
  const float* m_ij = (const float*)d_in[1];
  const int*   edges = (const int*)d_in[2];
  const float* Ww1 = (const float*)d_in[3];
  const float* bw1 = (const float*)d_in[4];
  const float* Ww2 = (const float*)d_in[5];
  const float* bw2 = (const float*)d_in[6];
  const float* Wa1 = (const float*)d_in[7];
  const float* ba1 = (const float*)d_in[8];
  const float* Wa2 = (const float*)d_in[9];
  const float* ba2 = (const float*)d_in[10];

  const int N = in_sizes[0] / 3;
  const int E = in_sizes[1] / MSG;
  const int* src = edges;        // edges[0] = receiver
  const int* dst = edges + E;    // edges[1] = neighbor

  // Workspace layout (~1.7 MB)
  char* p = (char*)d_ws;
  unsigned short* WtW = (unsigned short*)p; p += (size_t)MSG * MSG * 2;
  unsigned short* WtA = (unsigned short*)p; p += (size_t)MSG * MSG * 2;
  float* num4 = (float*)p; p += (size_t)N * 4 * 4;

  float* out = (float*)d_out;

  const int ntiles = (E + TILE - 1) / TILE;
  const int nb = ntiles < NB_MAX ? ntiles : NB_MAX;

  hipMemsetAsync(num4, 0, (size_t)N * 4 * 4, stream);
  prep_weights_kernel<<<(MSG * MSG + 255) / 256, 256, 0, stream>>>(Ww1, Wa1, WtW, WtA);
  edge_mlp_pipe_kernel<<<nb, TPB, 0, stream>>>(
      m_ij, WtW, WtA, bw1, Ww2, bw2, ba1, Wa2, ba2, src, dst, x, num4, E, ntiles);
  finalize_kernel<<<(N + 255) / 256, 256, 0, stream>>>(x, (const f32x4*)num4, out, N);
}

// Round 7
// 1195.866 us; speedup vs baseline: 1.4305x; 1.0304x over previous
//
#include <hip/hip_runtime.h>
#include <cmath>

#define MSG 128
#define TILE 64      // edges per LDS tile
#define TPB 512      // 8 waves; each wave owns 16 hidden units
#define NB_MAX 512   // 2 blocks/CU

typedef __attribute__((ext_vector_type(8))) __bf16 bf16x8;
typedef __attribute__((ext_vector_type(4))) float f32x4;

__device__ __forceinline__ unsigned short f2bf(float f) {
  union { float f; unsigned u; } v; v.f = f;
  unsigned r = v.u + 0x7FFFu + ((v.u >> 16) & 1u);  // round-to-nearest-even
  return (unsigned short)(r >> 16);
}

// ---- Kernel 1: convert + transpose both hidden-layer weight matrices to bf16.
__global__ void prep_weights_kernel(const float* __restrict__ Ww1,
                                    const float* __restrict__ Wa1,
                                    unsigned short* __restrict__ WtW,
                                    unsigned short* __restrict__ WtA) {
  int idx = blockIdx.x * blockDim.x + threadIdx.x;
  if (idx < MSG * MSG) {
    int k = idx >> 7;
    int n = idx & 127;
    WtW[n * MSG + k] = f2bf(Ww1[idx]);
    WtA[n * MSG + k] = f2bf(Wa1[idx]);
  }
}

__device__ __forceinline__ void gload_lds16(const float* g, float* l) {
  __builtin_amdgcn_global_load_lds(
      (const __attribute__((address_space(1))) void*)g,
      (__attribute__((address_space(3))) void*)l, 16, 0, 0);
}

// ---- Kernel 2: persistent 2-phase pipelined edge pass (8-wave blocks).
// Round-6 lesson: the finalize prefetch (src/dst -> dependent x gathers) sat
// BETWEEN stage() and compute; the compiler's s_waitcnt to consume the
// gathers drained the entire next-tile staging queue BEFORE compute ->
// period = delivery + compute (serial, ~20K cyc) instead of max(~7K).
// Fix: src/dst issued BEFORE stage() (older in vmcnt queue, so consuming
// them later never forces staging to drain); x gathers + finalize moved
// AFTER the compute loop; barrier-B wait made wave-uniform and correct
// (w<4: vmcnt(4) leaves only the 4 atomics in flight; w>=4: vmcnt(0)).
__global__ __launch_bounds__(TPB, 2)
void edge_mlp_pipe_kernel(const float* __restrict__ m_ij,
                          const unsigned short* __restrict__ WtW,
                          const unsigned short* __restrict__ WtA,
                          const float* __restrict__ bw1, const float* __restrict__ Ww2,
                          const float* __restrict__ bw2,
                          const float* __restrict__ ba1, const float* __restrict__ Wa2,
                          const float* __restrict__ ba2,
                          const int* __restrict__ src,
                          const int* __restrict__ dst,
                          const float* __restrict__ x,
                          float* __restrict__ num4, int E, int ntiles) {
  __shared__ __align__(16) float buf[2][TILE * MSG];  // 2 x 32KB, swizzled rows
  __shared__ float plds[2][8][TILE];                  // [mlp][wave][edge] 4KB

  const int tid = threadIdx.x;
  const int w = tid >> 6;
  const int lane = tid & 63;
  const int quad = lane >> 4;
  const int l16 = lane & 15;

  // --- Persistent weights: wave w owns hidden units [16w, 16w+16).
  // A-frag: A[m = 16w + l16][k = quad*8 + kt*32 + j].
  bf16x8 wf[2][4];     // [mat W/A][kt]
  f32x4 c1[2], c2[2];  // [mat]: layer-1 bias, layer-2 weight @ 16w + quad*4
  {
    const int unit16 = w * 16;
    const size_t ro = (size_t)(unit16 + l16) * MSG + quad * 8;
    #pragma unroll
    for (int kt = 0; kt < 4; ++kt) {
      wf[0][kt] = *(const bf16x8*)(WtW + ro + kt * 32);
      wf[1][kt] = *(const bf16x8*)(WtA + ro + kt * 32);
    }
    const int co = unit16 + quad * 4;
    c1[0] = *(const f32x4*)(bw1 + co);
    c2[0] = *(const f32x4*)(Ww2 + co);
    c1[1] = *(const f32x4*)(ba1 + co);
    c2[1] = *(const f32x4*)(Wa2 + co);
  }
  const float bw2s = bw2[0], ba2s = ba2[0];

  // Stage one 64x128 fp32 tile into buf[bsel]. LDS dest is linear; the XOR
  // swizzle (byte ^= (row&7)<<4, involution, row-preserving) is applied to the
  // GLOBAL source address (T21: both-sides-or-neither).
  auto stage = [&](int tile, int bsel) {
    #pragma unroll
    for (int i = 0; i < 4; ++i) {
      const int chunk = i * TPB + tid;        // 0..2047
      const int db = chunk * 16;              // dest byte in [0, 32768)
      const int row = db >> 9;                // tile row (512B rows)
      const int col = db & 511;
      const int scol = col ^ ((row & 7) << 4);
      int grow = tile * TILE + row;
      if (grow >= E) grow = E - 1;            // clamp (stores guarded later)
      const float* g = m_ij + (size_t)grow * MSG + (scol >> 2);
      gload_lds16(g, &buf[bsel][0] + (db >> 2));
    }
  };

  int tt = blockIdx.x;
  if (tt < ntiles) stage(tt, 0);
  asm volatile("s_waitcnt vmcnt(0)" ::: "memory");
  __builtin_amdgcn_s_barrier();
  int cur = 0;

  for (; tt < ntiles; tt += gridDim.x) {
    // Finalize ownership: waves 0..3, quad==0 lanes own 16 edges each.
    const int eL = w * 16 + l16;
    const int ge = tt * TILE + eL;
    const bool fown = (quad == 0) && (w < 4) && (ge < E);

    // (1) src/dst FIRST (oldest in vmcnt queue: consuming them later will
    //     never force the staging loads below to drain).
    int sN = 0, dN = 0;
    if (fown) { sN = src[ge]; dN = dst[ge]; }

    // (2) fire-and-forget staging of the next tile.
    const int nxt = tt + (int)gridDim.x;
    if (nxt < ntiles) stage(nxt, cur ^ 1);

    // (3) Compute: 4 edge sub-tiles of 16; B[k][n=edge] from swizzled LDS.
    #pragma unroll
    for (int et = 0; et < 4; ++et) {
      const int row = et * 16 + l16;
      const int rbase = row * MSG;            // float index
      const int xorf = (row & 7) << 2;        // float-index xor (= byte<<4)
      bf16x8 bf[4];
      #pragma unroll
      for (int kt = 0; kt < 4; ++kt) {
        const int c0 = quad * 8 + kt * 32;
        const f32x4 v0 = *(const f32x4*)(&buf[cur][rbase + (c0 ^ xorf)]);
        const f32x4 v1 = *(const f32x4*)(&buf[cur][rbase + ((c0 + 4) ^ xorf)]);
        bf16x8 f;
        f[0] = (__bf16)v0.x; f[1] = (__bf16)v0.y;
        f[2] = (__bf16)v0.z; f[3] = (__bf16)v0.w;
        f[4] = (__bf16)v1.x; f[5] = (__bf16)v1.y;
        f[6] = (__bf16)v1.z; f[7] = (__bf16)v1.w;
        bf[kt] = f;
      }
      f32x4 accW = {0.f, 0.f, 0.f, 0.f};
      f32x4 accA = {0.f, 0.f, 0.f, 0.f};
      #pragma unroll
      for (int kt = 0; kt < 4; ++kt) {
        accW = __builtin_amdgcn_mfma_f32_16x16x32_bf16(wf[0][kt], bf[kt], accW, 0, 0, 0);
        accA = __builtin_amdgcn_mfma_f32_16x16x32_bf16(wf[1][kt], bf[kt], accA, 0, 0, 0);
      }
      // Fused epilogue over this wave's 4 units/lane: silu(h)*W2 partials.
      float pW = 0.f, pA = 0.f;
      #pragma unroll
      for (int r = 0; r < 4; ++r) {
        const float hw = accW[r] + c1[0][r];
        const float ha = accA[r] + c1[1][r];
        // silu via rcp: saturation-safe (exp(-h)->inf => rcp->0 => silu->0).
        pW += (hw * c2[0][r]) * __builtin_amdgcn_rcpf(1.f + __expf(-hw));
        pA += (ha * c2[1][r]) * __builtin_amdgcn_rcpf(1.f + __expf(-ha));
      }
      pW += __shfl_xor(pW, 16, 64); pW += __shfl_xor(pW, 32, 64);
      pA += __shfl_xor(pA, 16, 64); pA += __shfl_xor(pA, 32, 64);
      if (quad == 0) {
        plds[0][w][et * 16 + l16] = pW;
        plds[1][w][et * 16 + l16] = pA;
      }
    }

    // Barrier A: partials visible to all waves.
    asm volatile("s_waitcnt lgkmcnt(0)" ::: "memory");
    __builtin_amdgcn_s_barrier();

    // (4) Finalize AFTER compute: the wait for sN/dN + x gathers lands here,
    //     where the staging drain belongs anyway (not before compute).
    if (fown) {
      const float sx = x[3 * sN], sy = x[3 * sN + 1], sz = x[3 * sN + 2];
      const float gx = x[3 * dN], gy = x[3 * dN + 1], gz = x[3 * dN + 2];
      float sW = 0.f, sA = 0.f;
      #pragma unroll
      for (int ww = 0; ww < 8; ++ww) {
        sW += plds[0][ww][eL];
        sA += plds[1][ww][eL];
      }
      const float a = __expf(sA + ba2s);
      const float t = (sW + bw2s) * a;  // w*a; /a_i deferred to finalize kernel
      const float dx = gx - sx, dy = gy - sy, dz = gz - sz;
      const float nrm = sqrtf(dx * dx + dy * dy + dz * dz);
      const float inv = t * __builtin_amdgcn_rcpf(fmaxf(nrm, 1e-12f));
      float* basep = num4 + (size_t)4 * sN;
      atomicAdd(basep + 0, dx * inv);
      atomicAdd(basep + 1, dy * inv);
      atomicAdd(basep + 2, dz * inv);
      atomicAdd(basep + 3, a);
    }

    // Barrier B: next tile's staging must be in LDS for ALL waves.
    // Wave-uniform split (w is uniform): waves 0..3 leave only their 4
    // atomics outstanding; waves 4..7 drain their staging fully.
    if (w < 4) {
      asm volatile("s_waitcnt vmcnt(4) lgkmcnt(0)" ::: "memory");
    } else {
      asm volatile("s_waitcnt vmcnt(0) lgkmcnt(0)" ::: "memory");
    }
    __builtin_amdgcn_s_barrier();
    cur ^= 1;
  }
}

// ---- Kernel 3: per-node finalize. out = x + num.xyz / num.w (0 if no edges).
__global__ void finalize_kernel(const float* __restrict__ x,
                                const f32x4* __restrict__ num4,
                                float* __restrict__ out, int N) {
  int n = blockIdx.x * blockDim.x + threadIdx.x;
  if (n >= N) return;
  const f32x4 v = num4[n];
  const float inv = (v[3] != 0.f) ? __builtin_amdgcn_rcpf(v[3]) : 0.f;
  out[3 * n + 0] = x[3 * n + 0] + v[0] * inv;
  out[3 * n + 1] = x[3 * n + 1] + v[1] * inv;
  out[3 * n + 2] = x[3 * n + 2] + v[2] * inv;
}

extern "C" void kernel_launch(void* const* d_in, const int* in_sizes, int n_in,
                              void* d_out, int out_size, void* d_ws, size_t ws_size,
                              hipStream_t stream) {
  const float* x    = (const float*)d_in[0];
  const float* m_ij = (const float*)d_in[1];
  const int*   edges = (const int*)d_in[2];
  const float* Ww1 = (const float*)d_in[3];
  const float* bw1 = (const float*)d_in[4];
  const float* Ww2 = (const float*)d_in[5];
  const float* bw2 = (const float*)d_in[6];
  const float* Wa1 = (const float*)d_in[7];
  const float* ba1 = (const float*)d_in[8];
  const float* Wa2 = (const float*)d_in[9];
  const float* ba2 = (const float*)d_in[10];

  const int N = in_sizes[0] / 3;
  const int E = in_sizes[1] / MSG;
  const int* src = edges;        // edges[0] = receiver
  const int* dst = edges + E;    // edges[1] = neighbor

  // Workspace layout (~1.7 MB)
  char* p = (char*)d_ws;
  unsigned short* WtW = (unsigned short*)p; p += (size_t)MSG * MSG * 2;
  unsigned short* WtA = (unsigned short*)p; p += (size_t)MSG * MSG * 2;
  float* num4 = (float*)p; p += (size_t)N * 4 * 4;

  float* out = (float*)d_out;

  const int ntiles = (E + TILE - 1) / TILE;
  const int nb = ntiles < NB_MAX ? ntiles : NB_MAX;

  hipMemsetAsync(num4, 0, (size_t)N * 4 * 4, stream);
  prep_weights_kernel<<<(MSG * MSG + 255) / 256, 256, 0, stream>>>(Ww1, Wa1, WtW, WtA);
  edge_mlp_pipe_kernel<<<nb, TPB, 0, stream>>>(
      m_ij, WtW, WtA, bw1, Ww2, bw2, ba1, Wa2, ba2, src, dst, x, num4, E, ntiles);
  finalize_kernel<<<(N + 255) / 256, 256, 0, stream>>>(x, (const f32x4*)num4, out, N);
}